// Round 7
// baseline (64.227 us; speedup 1.0000x reference)
//
#include <hip/hip_runtime.h>
#include <hip/hip_cooperative_groups.h>

namespace cg = cooperative_groups;

#define NB 4
#define NC 128
#define NH 128
#define NW 128
#define EPSV 0.2f
#define TH 2

typedef float v4f __attribute__((ext_vector_type(4)));

// Cooperative fused kernel. 256 blocks = (b, h-pair), XCD-swizzled, 512 thr.
// Phase A': channel-mean of OWN rows h0,h0+1 only (each x row read exactly
//           once device-wide) -> global meanbuf.  grid.sync().
// Phase B : reload 4 mean rows, 9-tap softmax weights -> LDS.
// Phase C : reassembly, 16B nontemporal float4 stores (NT proven +4us in R6).
__global__ __launch_bounds__(512) void fused_carafe(const float* __restrict__ x,
                                                    float* __restrict__ meanbuf,
                                                    float* __restrict__ out) {
    const int chunk = gridDim.x >> 3;            // 32
    const int bid = blockIdx.x;
    const int swz = (bid & 7) * chunk + (bid >> 3);
    const int b  = swz >> 6;
    const int h0 = (swz & 63) * TH;

    __shared__ float partial[2][2][NW];          // [chalf][r][w] 4 KB
    __shared__ float mrow[4][NW];                // mean rows h0-1..h0+2
    __shared__ float wgt[TH][9][NW];             // 9 KB

    const int tid = threadIdx.x;

    // ---------------- Phase A': own-row channel means ----------------
    {
        const int w    = tid & 127;
        const int r    = (tid >> 7) & 1;         // own row h0+r
        const int half = tid >> 8;               // channel half
        const int h = h0 + r;
        const float* px = x + (((size_t)(b * NC + half * 64)) * NH + h) * NW + w;
        float s = 0.f;
        #pragma unroll 16
        for (int c = 0; c < 64; ++c)
            s += px[(size_t)c * NH * NW];
        partial[half][r][w] = s;
    }
    __syncthreads();
    if (tid < 256) {
        const int w = tid & 127;
        const int r = tid >> 7;
        const float m = (partial[0][r][w] + partial[1][r][w]) * (1.0f / NC);
        meanbuf[((size_t)b * NH + h0 + r) * NW + w] = m;
    }

    cg::this_grid().sync();

    // ---------------- stage 4 mean rows ----------------
    {
        const int w = tid & 127;
        const int r = tid >> 7;                  // 0..3
        const int hh = h0 - 1 + r;
        mrow[r][w] = (hh >= 0 && hh < NH)
                         ? meanbuf[((size_t)b * NH + hh) * NW + w] : 0.f;
    }
    __syncthreads();

    // ---------------- Phase B: softmax weights ----------------
    if (tid < 256) {
        const int r = tid >> 7;                  // source row h0+r
        const int w = tid & 127;
        const float mc = mrow[r + 1][w];
        float v[9];
        float vmax = -1e30f;
        #pragma unroll
        for (int ky = 0; ky < 3; ++ky) {
            #pragma unroll
            for (int kx = -1; kx <= 1; ++kx) {
                const int ww = w + kx;
                const float mp = (ww >= 0 && ww < NW) ? mrow[r + ky][ww] : 0.f;
                const float g = mp - mc;
                const float val = 1.0f / (g * g + EPSV);
                v[ky * 3 + kx + 1] = val;
                vmax = fmaxf(vmax, val);
            }
        }
        float sum = 0.f;
        #pragma unroll
        for (int k = 0; k < 9; ++k) { v[k] = __expf(v[k] - vmax); sum += v[k]; }
        const float rs = 1.0f / sum;
        #pragma unroll
        for (int k = 0; k < 9; ++k) wgt[r][k][w] = v[k] * rs;
    }
    __syncthreads();

    // ---------------- Phase C: reassembly ----------------
    const int wp = tid & 63;                     // source cols 2wp, 2wp+1
    const int cg_ = tid >> 6;                    // 0..7 -> 16 channels each
    const int wa = 2 * wp;

    float wA0[9], wB0[9], wA1[9], wB1[9];
    #pragma unroll
    for (int k = 0; k < 9; ++k) {
        wA0[k] = wgt[0][k][wa];  wB0[k] = wgt[0][k][wa + 1];
        wA1[k] = wgt[1][k][wa];  wB1[k] = wgt[1][k][wa + 1];
    }

    const bool rv0 = (h0 > 0), rv3 = (h0 + 2 < NH);
    const bool tv0 = (wp > 0), tv3 = (wp < 63);

    #pragma unroll 2
    for (int i = 0; i < 16; ++i) {
        const int c = cg_ * 16 + i;
        const float* xc = x + ((size_t)(b * NC + c)) * (NH * NW);

        float a[4][4];                           // rows h0-1..h0+2, taps wa-1..wa+2
        #pragma unroll
        for (int rr = 0; rr < 4; ++rr) {
            const int hh = h0 - 1 + rr;
            const bool rv = (rr == 0) ? rv0 : ((rr == 3) ? rv3 : true);
            const float* row = xc + hh * NW + wa;
            a[rr][0] = (rv && tv0) ? row[-1] : 0.f;
            a[rr][1] = rv ? row[0] : 0.f;
            a[rr][2] = rv ? row[1] : 0.f;
            a[rr][3] = (rv && tv3) ? row[2] : 0.f;
        }

        float v0a = 0.f, v0b = 0.f, v1a = 0.f, v1b = 0.f;
        #pragma unroll
        for (int ky = 0; ky < 3; ++ky) {
            #pragma unroll
            for (int kx = 0; kx < 3; ++kx) {
                const int k = ky * 3 + kx;
                v0a += wA0[k] * a[ky][kx];
                v0b += wB0[k] * a[ky][kx + 1];
                v1a += wA1[k] * a[ky + 1][kx];
                v1b += wB1[k] * a[ky + 1][kx + 1];
            }
        }

        float* o = out + ((size_t)(b * NC + c) * (NH * 2) + 2 * h0) * (NW * 2) + 4 * wp;
        const v4f p0 = {v0a, v0a, v0b, v0b};
        const v4f p1 = {v1a, v1a, v1b, v1b};
        __builtin_nontemporal_store(p0, (v4f*)(o));
        __builtin_nontemporal_store(p0, (v4f*)(o + (NW * 2)));
        __builtin_nontemporal_store(p1, (v4f*)(o + 2 * (NW * 2)));
        __builtin_nontemporal_store(p1, (v4f*)(o + 3 * (NW * 2)));
    }
}

extern "C" void kernel_launch(void* const* d_in, const int* in_sizes, int n_in,
                              void* d_out, int out_size, void* d_ws, size_t ws_size,
                              hipStream_t stream) {
    const float* x = (const float*)d_in[0];
    float* out = (float*)d_out;
    float* meanbuf = (float*)d_ws;               // 256 KB, fully rewritten each call

    void* args[] = {(void*)&x, (void*)&meanbuf, (void*)&out};
    hipLaunchCooperativeKernel((void*)fused_carafe, dim3(NB * NH / TH), dim3(512),
                               args, 0, stream);
}